// Round 17
// baseline (1020.741 us; speedup 1.0000x reference)
//
#include <hip/hip_runtime.h>
#include <hip/hip_bf16.h>

#define M_ROWS 16384
#define D_DIM  1024
#define K_CB   4096

#define ZTILE  128               // z rows per block
#define CTILE  256               // cb entries per chunk
#define NS     8
#define COLS_PER_SPLIT (K_CB / NS)   // 512
#define BODIES 32                    // 2 chunks x 16 (K=1024 / 64 per body)
#define MBLOCKS (M_ROWS / ZTILE)     // 128

typedef __attribute__((ext_vector_type(4))) int  int4v;
typedef __attribute__((ext_vector_type(8))) int  int8v;
typedef __attribute__((ext_vector_type(16))) float f32x16;

static __device__ __forceinline__ unsigned f2sortable(float f) {
  unsigned u = __float_as_uint(f);
  return (u & 0x80000000u) ? ~u : (u | 0x80000000u);
}

static __device__ __forceinline__ float sortable2f(unsigned s) {
  unsigned u = (s & 0x80000000u) ? (s ^ 0x80000000u) : ~s;
  return __uint_as_float(u);
}

// OCP e4m3fn encode, RNE, satfinite.
static __device__ __forceinline__ unsigned char f2e4m3(float f) {
  float a = fabsf(f);
  const unsigned s = (__float_as_uint(f) >> 24) & 0x80u;
  if (a < 0.015625f) {                       // subnormal range (< 2^-6)
    int m = (int)(a * 512.0f + 0.5f);        // round(a / 2^-9)
    if (m >= 8) return (unsigned char)(s | 0x08u);   // -> 2^-6 normal
    return (unsigned char)(s | (unsigned)m);
  }
  if (a > 448.0f) a = 448.0f;
  unsigned t = __float_as_uint(a);
  t += 0x7FFFFu + ((t >> 20) & 1u);          // RNE to 3 mantissa bits
  int e = (int)(t >> 23) - 127;
  unsigned m = (t >> 20) & 7u;
  if (e > 8 || (e == 8 && m == 7u)) { e = 8; m = 6u; }   // clamp to 448
  return (unsigned char)(s | ((unsigned)(e + 7) << 3) | m);
}

// ---------------- Kernel 1: l2-normalize rows -> fp8 e4m3 (x16, row-major) ----------------
// Output scaled by 16 (e4m3 sweet range); both operands scaled the same way
// -> dot x256, top-k order preserved; k3 rescales (SCALE = 10/256).
__global__ __launch_bounds__(256)
void k_normalize(const float* __restrict__ z, const float* __restrict__ cb,
                 unsigned char* __restrict__ zf8, unsigned char* __restrict__ cbf8) {
  const int bid = blockIdx.x;
  const float* src;
  unsigned char* dst;
  if (bid < M_ROWS) {
    src = z + (size_t)bid * D_DIM;
    dst = zf8 + (size_t)bid * D_DIM;
  } else {
    const int r = bid - M_ROWS;
    src = cb + (size_t)r * D_DIM;
    dst = cbf8 + (size_t)r * D_DIM;
  }
  const int t = threadIdx.x;
  const float4 v = ((const float4*)src)[t];
  float ss = v.x * v.x + v.y * v.y + v.z * v.z + v.w * v.w;
#pragma unroll
  for (int off = 32; off > 0; off >>= 1) ss += __shfl_down(ss, off, 64);
  __shared__ float sp[4];
  if ((t & 63) == 0) sp[t >> 6] = ss;
  __syncthreads();
  const float tot = sp[0] + sp[1] + sp[2] + sp[3];
  const float sc = 16.0f / sqrtf(tot + 1e-12f);     // l2norm * 16
  uchar4 o;
  o.x = f2e4m3(v.x * sc);
  o.y = f2e4m3(v.y * sc);
  o.z = f2e4m3(v.z * sc);
  o.w = f2e4m3(v.w * sc);
  *(uchar4*)(dst + 4 * t) = o;
}

// ---------------- Kernel 2: z128 x cb256, MX-scaled fp8 32x32x64, LDS-FREE ----------------
// All inputs are L2-resident (cb slab 512 KB/XCD, z tiles ~2 MB/XCD; HBM
// steady-state fetch was 4 MB) and the 32x32x64 fragment = 32 CONTIGUOUS
// bytes per lane in row-major global layout (lane l: row l&31, bytes
// [32*l5, 32*l5+32); lanes i,i+32 cover one full 64B line). So fragments
// load straight from L2 -- no staging, no swizzle, NO BARRIERS in the loop
// (Common-mistake #7: don't LDS-stage L2-fit data). Register double-buffer
// (static names, rule #20), loads issued one body ahead; waves free-run.
// R16's LDS pipe cost (~900 cy/body/CU reads+writes+conflicts vs 270 cy
// MFMA) disappears; bound moves to L2 BW (~1.6 GB @ 34.5 TB/s ~ 46 us).
__global__ __launch_bounds__(256, 2)
void k_gemm_topk(const unsigned char* __restrict__ zf8,
                 const unsigned char* __restrict__ cbf8,
                 unsigned* __restrict__ part) {
  __shared__ unsigned mrg[ZTILE * 33];   // merge scratch only (16.9 KB)

  const int tid  = threadIdx.x;
  const int lane = tid & 63;
  const int wid  = tid >> 6;
  const int wc   = wid & 1;    // cb 128-block
  const int wz   = wid >> 1;   // z 64-block
  const int l31  = lane & 31;
  const int l5   = lane >> 5;

  const int wgid  = (int)blockIdx.x;
  const int split = wgid & 7;          // xcd-resident codebook slab
  const int mtile = wgid >> 3;
  const int rbase = mtile * ZTILE;
  const int cbase = split * COLS_PER_SPLIT;

  // per-lane constant byte offsets (k=0); body adds uniform kc_/kz_
  long co[4], zo[2];
#pragma unroll
  for (int mi = 0; mi < 4; ++mi)
    co[mi] = (long)(cbase + wc * 128 + mi * 32 + l31) * D_DIM + l5 * 32;
#pragma unroll
  for (int nj = 0; nj < 2; ++nj)
    zo[nj] = (long)(rbase + wz * 64 + nj * 32 + l31) * D_DIM + l5 * 32;

  f32x16 acc[4][2];
#pragma unroll
  for (int mi = 0; mi < 4; ++mi)
#pragma unroll
    for (int nj = 0; nj < 2; ++nj)
#pragma unroll
      for (int r = 0; r < 16; ++r) acc[mi][nj][r] = 0.f;

  unsigned tk[2][8];                 // sorted ascending; tk[0] = min; pure u32
#pragma unroll
  for (int l = 0; l < 2; ++l)
#pragma unroll
    for (int q = 0; q < 8; ++q) tk[l][q] = 0u;

  int4v cfA[4][2], zrA[2][2];        // register double-buffer, static names
  int4v cfB[4][2], zrB[2][2];

#define LOADF(CF, ZR, BB) do { \
  const long kc_ = (((long)((BB) >> 4)) << 18) + (long)(((BB) & 15) << 6); \
  const long kz_ = (long)(((BB) & 15) << 6); \
  _Pragma("unroll") for (int mi = 0; mi < 4; ++mi) { \
    CF[mi][0] = *(const int4v*)(cbf8 + kc_ + co[mi]); \
    CF[mi][1] = *(const int4v*)(cbf8 + kc_ + co[mi] + 16); \
  } \
  _Pragma("unroll") for (int nj = 0; nj < 2; ++nj) { \
    ZR[nj][0] = *(const int4v*)(zf8 + kz_ + zo[nj]); \
    ZR[nj][1] = *(const int4v*)(zf8 + kz_ + zo[nj] + 16); \
  } \
} while (0)

#define MM(CF, ZR) do { \
  __builtin_amdgcn_s_setprio(1); \
  _Pragma("unroll") for (int mi = 0; mi < 4; ++mi) \
  _Pragma("unroll") for (int nj = 0; nj < 2; ++nj) { \
    const int8v a_ = __builtin_shufflevector(CF[mi][0], CF[mi][1], 0, 1, 2, 3, 4, 5, 6, 7); \
    const int8v b_ = __builtin_shufflevector(ZR[nj][0], ZR[nj][1], 0, 1, 2, 3, 4, 5, 6, 7); \
    acc[mi][nj] = __builtin_amdgcn_mfma_scale_f32_32x32x64_f8f6f4( \
        a_, b_, acc[mi][nj], 0 /*A=fp8*/, 0 /*B=fp8*/, 0, 0x7F, 0, 0x7F); \
  } \
  __builtin_amdgcn_s_setprio(0); \
} while (0)

  auto EPILOGUE = [&](int chunk) {
    const int cfb0 = cbase + chunk * CTILE + wc * 128 + l5 * 4;
#pragma unroll
    for (int nj = 0; nj < 2; ++nj) {
#pragma unroll
      for (int mi = 0; mi < 4; ++mi) {
#pragma unroll
        for (int r = 0; r < 16; ++r) {
          const float v = acc[mi][nj][r];
          const unsigned idx = (unsigned)(cfb0 + mi * 32 + (r & 3) + ((r >> 2) << 3));
          const unsigned key = (f2sortable(v) & ~0xFFFu) | idx;
          if (key > tk[nj][0]) {               // pure u32 gate; sorted insert
            unsigned cur = key;
#pragma unroll
            for (int q = 0; q < 7; ++q) {
              const unsigned a = tk[nj][q + 1];
              tk[nj][q] = (a < cur) ? a : cur;
              cur       = (a < cur) ? cur : a;
            }
            tk[nj][7] = cur;
          }
          acc[mi][nj][r] = 0.f;
        }
      }
    }
  };

  LOADF(cfA, zrA, 0);
  for (int b = 0; b < BODIES; b += 2) {
    LOADF(cfB, zrB, b + 1);            // prefetch next body
    MM(cfA, zrA);                      // body b
    if (b + 2 < BODIES) LOADF(cfA, zrA, b + 2);
    MM(cfB, zrB);                      // body b+1
    if (b == 14) EPILOGUE(0);          // chunk 0 done after body 15
    if (b == 30) EPILOGUE(1);          // chunk 1 done after body 31
  }

  // merge: per z row 4 contributors (wc x l5) x 8 keys -> LDS, then top-8 scan
  __syncthreads();
  {
    const int slotw = (wc * 2 + l5) * 8;
#pragma unroll
    for (int nj = 0; nj < 2; ++nj) {
      const int zrow = wz * 64 + nj * 32 + l31;
#pragma unroll
      for (int q = 0; q < 8; ++q) mrg[zrow * 33 + slotw + q] = tk[nj][q];
    }
  }
  __syncthreads();
  if (tid < ZTILE) {
    const unsigned* c = mrg + tid * 33;
    unsigned top[8];
#pragma unroll
    for (int p = 0; p < 8; ++p) top[p] = 0u;
    unsigned tmin = 0u;
    for (int q0 = 0; q0 < 32; ++q0) {
      const unsigned k = c[(q0 + tid) & 31];   // rotate to spread banks
      if (k > tmin) {
        int ms = 0;
        unsigned mv = top[0];
#pragma unroll
        for (int q = 1; q < 8; ++q) { if (top[q] < mv) { mv = top[q]; ms = q; } }
#pragma unroll
        for (int q = 0; q < 8; ++q) top[q] = (q == ms) ? k : top[q];
        mv = top[0];
#pragma unroll
        for (int q = 1; q < 8; ++q) mv = (top[q] < mv) ? top[q] : mv;
        tmin = mv;
      }
    }
    unsigned* dst = part + ((size_t)(rbase + tid) * NS + split) * 8;
#pragma unroll
    for (int p = 0; p < 8; ++p) dst[p] = top[p];
  }
}

// ---------------- Kernel 3: merge splits, softmax, gather E, gate ----------------
// logits computed on x16-scaled operands -> raw dot = 256x; softmax input is
// TAU * dot / 256.
template<int NSP>
__global__ __launch_bounds__(256)
void k_gate(const unsigned* __restrict__ part, const float* __restrict__ target,
            const float* __restrict__ E, float* __restrict__ out) {
  constexpr int NK = NSP * 8;
  const int row = blockIdx.x;
  const int t = threadIdx.x;
  __shared__ float s_alpha[8];
  __shared__ int s_idx[8];
  __shared__ unsigned s_key[8];

  if (t < NK) {
    unsigned k = part[(size_t)row * NK + t];
#pragma unroll
    for (int p = 0; p < 8; ++p) {
      unsigned m = k;
#pragma unroll
      for (int off = NK / 2; off > 0; off >>= 1) {
        const unsigned o = __shfl_xor(m, off, NK);
        m = (m > o) ? m : o;
      }
      if (k == m) { s_key[p] = k; k = 0u; }  // keys distinct (idx in low bits)
    }
  }
  __syncthreads();
  if (t < 8) {
    const float SCALE = 10.0f / 256.0f;
    const unsigned key = s_key[t];
    const float val  = SCALE * sortable2f(key & ~0xFFFu);
    const float vmax = SCALE * sortable2f(s_key[0] & ~0xFFFu);
    const float e = expf(val - vmax);
    float s = e;
#pragma unroll
    for (int off = 4; off > 0; off >>= 1) s += __shfl_xor(s, off, 8);
    s_alpha[t] = e / s;
    s_idx[t] = (int)(key & 0xFFFu);
  }
  __syncthreads();

  float4 g = {0.f, 0.f, 0.f, 0.f};
#pragma unroll
  for (int p = 0; p < 8; ++p) {
    const float a = s_alpha[p];
    const float4 e4 = ((const float4*)E)[(size_t)s_idx[p] * 256 + t];
    g.x += a * e4.x;
    g.y += a * e4.y;
    g.z += a * e4.z;
    g.w += a * e4.w;
  }
  const float4 tg = ((const float4*)target)[(size_t)row * 256 + t];
  float4 o;
  o.x = tg.x * (1.f + g.x);
  o.y = tg.y * (1.f + g.y);
  o.z = tg.z * (1.f + g.z);
  o.w = tg.w * (1.f + g.w);
  ((float4*)out)[(size_t)row * 256 + t] = o;
}

extern "C" void kernel_launch(void* const* d_in, const int* in_sizes, int n_in,
                              void* d_out, int out_size, void* d_ws, size_t ws_size,
                              hipStream_t stream) {
  const float* z      = (const float*)d_in[0];
  const float* target = (const float*)d_in[1];
  const float* cb     = (const float*)d_in[2];
  const float* E      = (const float*)d_in[3];
  float* out = (float*)d_out;

  // d_out doubles as scratch for the fp8 normalized matrices (dead before k_gate writes)
  unsigned char* zf8  = (unsigned char*)d_out;                        // 16 MB
  unsigned char* cbf8 = (unsigned char*)d_out + 16777216;             // 4 MB @ +16MB
  unsigned* part = (unsigned*)d_ws;                                   // 4 MB

  k_normalize<<<dim3(M_ROWS + K_CB), dim3(256), 0, stream>>>(z, cb, zf8, cbf8);
  k_gemm_topk<<<dim3(MBLOCKS * NS), dim3(256), 0, stream>>>(zf8, cbf8, part);
  k_gate<NS><<<dim3(M_ROWS), dim3(256), 0, stream>>>(part, target, E, out);
}

// Round 18
// 303.359 us; speedup vs baseline: 3.3648x; 3.3648x over previous
//
#include <hip/hip_runtime.h>
#include <hip/hip_bf16.h>

#define M_ROWS 16384
#define D_DIM  1024
#define K_CB   4096

#define ZTILE  128               // z rows per block
#define CTILE  256               // cb entries per chunk
#define NS     8
#define COLS_PER_SPLIT (K_CB / NS)   // 512
#define BODIES 32                    // 2 chunks x 16 (K=1024 / 64 per body)
#define MBLOCKS (M_ROWS / ZTILE)     // 128

typedef __attribute__((ext_vector_type(8))) int  int8v;
typedef __attribute__((ext_vector_type(16))) float f32x16;

static __device__ __forceinline__ unsigned f2sortable(float f) {
  unsigned u = __float_as_uint(f);
  return (u & 0x80000000u) ? ~u : (u | 0x80000000u);
}

static __device__ __forceinline__ float sortable2f(unsigned s) {
  unsigned u = (s & 0x80000000u) ? (s ^ 0x80000000u) : ~s;
  return __uint_as_float(u);
}

// OCP e4m3fn encode, RNE, satfinite.
static __device__ __forceinline__ unsigned char f2e4m3(float f) {
  float a = fabsf(f);
  const unsigned s = (__float_as_uint(f) >> 24) & 0x80u;
  if (a < 0.015625f) {                       // subnormal range (< 2^-6)
    int m = (int)(a * 512.0f + 0.5f);        // round(a / 2^-9)
    if (m >= 8) return (unsigned char)(s | 0x08u);   // -> 2^-6 normal
    return (unsigned char)(s | (unsigned)m);
  }
  if (a > 448.0f) a = 448.0f;
  unsigned t = __float_as_uint(a);
  t += 0x7FFFFu + ((t >> 20) & 1u);          // RNE to 3 mantissa bits
  int e = (int)(t >> 23) - 127;
  unsigned m = (t >> 20) & 7u;
  if (e > 8 || (e == 8 && m == 7u)) { e = 8; m = 6u; }   // clamp to 448
  return (unsigned char)(s | ((unsigned)(e + 7) << 3) | m);
}

// ---------------- Kernel 1: l2-normalize rows -> fp8 e4m3 (x16, row-major) ----------------
// Output scaled by 16 (e4m3 sweet range); both operands scaled the same way
// -> dot x256, top-k order preserved; k3 rescales (SCALE = 10/256).
__global__ __launch_bounds__(256)
void k_normalize(const float* __restrict__ z, const float* __restrict__ cb,
                 unsigned char* __restrict__ zf8, unsigned char* __restrict__ cbf8) {
  const int bid = blockIdx.x;
  const float* src;
  unsigned char* dst;
  if (bid < M_ROWS) {
    src = z + (size_t)bid * D_DIM;
    dst = zf8 + (size_t)bid * D_DIM;
  } else {
    const int r = bid - M_ROWS;
    src = cb + (size_t)r * D_DIM;
    dst = cbf8 + (size_t)r * D_DIM;
  }
  const int t = threadIdx.x;
  const float4 v = ((const float4*)src)[t];
  float ss = v.x * v.x + v.y * v.y + v.z * v.z + v.w * v.w;
#pragma unroll
  for (int off = 32; off > 0; off >>= 1) ss += __shfl_down(ss, off, 64);
  __shared__ float sp[4];
  if ((t & 63) == 0) sp[t >> 6] = ss;
  __syncthreads();
  const float tot = sp[0] + sp[1] + sp[2] + sp[3];
  const float sc = 16.0f / sqrtf(tot + 1e-12f);     // l2norm * 16
  uchar4 o;
  o.x = f2e4m3(v.x * sc);
  o.y = f2e4m3(v.y * sc);
  o.z = f2e4m3(v.z * sc);
  o.w = f2e4m3(v.w * sc);
  *(uchar4*)(dst + 4 * t) = o;
}

// ---------------- Kernel 2: z128 x cb256, MX-scaled fp8 32x32x64, LDS-FREE ----------------
// R17 concept (inputs L2-resident; fragment = 32 contiguous bytes/lane in
// row-major global layout -> no staging, no swizzle, no loop barriers) with
// the register budget fixed: SINGLE-buffered int8v fragments loaded by
// direct 32B dereference (2x dwordx4 into one 8-reg tuple, no shufflevector
// copies). Budget: acc 128 AGPR + cf 32 + zr 16 + addr/tk/misc ~45 = ~220
// <= 256 unified @ 2 waves/SIMD. Cross-wave overlap (no barriers) hides L2
// latency (~300cy) under the other wave's MFMA wall (550cy). R17's spill
// (VGPR cap blown by dbuf+shuffle copies -> 2.3GB scratch) is the only diff.
__global__ __launch_bounds__(256, 2)
void k_gemm_topk(const unsigned char* __restrict__ zf8,
                 const unsigned char* __restrict__ cbf8,
                 unsigned* __restrict__ part) {
  __shared__ unsigned mrg[ZTILE * 33];   // merge scratch only (16.9 KB)

  const int tid  = threadIdx.x;
  const int lane = tid & 63;
  const int wid  = tid >> 6;
  const int wc   = wid & 1;    // cb 128-block
  const int wz   = wid >> 1;   // z 64-block
  const int l31  = lane & 31;
  const int l5   = lane >> 5;

  const int wgid  = (int)blockIdx.x;
  const int split = wgid & 7;          // xcd-resident codebook slab
  const int mtile = wgid >> 3;
  const int rbase = mtile * ZTILE;
  const int cbase = split * COLS_PER_SPLIT;

  // per-lane constant byte offsets (k=0); body adds uniform kc_/kz_
  long co[4], zo[2];
#pragma unroll
  for (int mi = 0; mi < 4; ++mi)
    co[mi] = (long)(cbase + wc * 128 + mi * 32 + l31) * D_DIM + l5 * 32;
#pragma unroll
  for (int nj = 0; nj < 2; ++nj)
    zo[nj] = (long)(rbase + wz * 64 + nj * 32 + l31) * D_DIM + l5 * 32;

  f32x16 acc[4][2];
#pragma unroll
  for (int mi = 0; mi < 4; ++mi)
#pragma unroll
    for (int nj = 0; nj < 2; ++nj)
#pragma unroll
      for (int r = 0; r < 16; ++r) acc[mi][nj][r] = 0.f;

  unsigned tk[2][8];                 // sorted ascending; tk[0] = min; pure u32
#pragma unroll
  for (int l = 0; l < 2; ++l)
#pragma unroll
    for (int q = 0; q < 8; ++q) tk[l][q] = 0u;

  int8v cf[4], zr[2];                // single-buffered fragments (48 VGPR)

  auto EPILOGUE = [&](int chunk) {
    const int cfb0 = cbase + chunk * CTILE + wc * 128 + l5 * 4;
#pragma unroll
    for (int nj = 0; nj < 2; ++nj) {
#pragma unroll
      for (int mi = 0; mi < 4; ++mi) {
#pragma unroll
        for (int r = 0; r < 16; ++r) {
          const float v = acc[mi][nj][r];
          const unsigned idx = (unsigned)(cfb0 + mi * 32 + (r & 3) + ((r >> 2) << 3));
          const unsigned key = (f2sortable(v) & ~0xFFFu) | idx;
          if (key > tk[nj][0]) {               // pure u32 gate; sorted insert
            unsigned cur = key;
#pragma unroll
            for (int q = 0; q < 7; ++q) {
              const unsigned a = tk[nj][q + 1];
              tk[nj][q] = (a < cur) ? a : cur;
              cur       = (a < cur) ? cur : a;
            }
            tk[nj][7] = cur;
          }
          acc[mi][nj][r] = 0.f;
        }
      }
    }
  };

  for (int b = 0; b < BODIES; ++b) {
    const long kc = (((long)(b >> 4)) << 18) + (long)((b & 15) << 6);  // chunk*256*1024 + k*64
    const long kz = (long)((b & 15) << 6);
#pragma unroll
    for (int mi = 0; mi < 4; ++mi) cf[mi] = *(const int8v*)(cbf8 + kc + co[mi]);
#pragma unroll
    for (int nj = 0; nj < 2; ++nj) zr[nj] = *(const int8v*)(zf8 + kz + zo[nj]);

    __builtin_amdgcn_s_setprio(1);
#pragma unroll
    for (int mi = 0; mi < 4; ++mi)
#pragma unroll
      for (int nj = 0; nj < 2; ++nj)
        acc[mi][nj] = __builtin_amdgcn_mfma_scale_f32_32x32x64_f8f6f4(
            cf[mi], zr[nj], acc[mi][nj],
            0 /*A=fp8 e4m3*/, 0 /*B=fp8 e4m3*/, 0, 0x7F, 0, 0x7F);
    __builtin_amdgcn_s_setprio(0);

    if (b == 15) EPILOGUE(0);
  }
  EPILOGUE(1);

  // merge: per z row 4 contributors (wc x l5) x 8 keys -> LDS, then top-8 scan
  __syncthreads();
  {
    const int slotw = (wc * 2 + l5) * 8;
#pragma unroll
    for (int nj = 0; nj < 2; ++nj) {
      const int zrow = wz * 64 + nj * 32 + l31;
#pragma unroll
      for (int q = 0; q < 8; ++q) mrg[zrow * 33 + slotw + q] = tk[nj][q];
    }
  }
  __syncthreads();
  if (tid < ZTILE) {
    const unsigned* c = mrg + tid * 33;
    unsigned top[8];
#pragma unroll
    for (int p = 0; p < 8; ++p) top[p] = 0u;
    unsigned tmin = 0u;
    for (int q0 = 0; q0 < 32; ++q0) {
      const unsigned k = c[(q0 + tid) & 31];   // rotate to spread banks
      if (k > tmin) {
        int ms = 0;
        unsigned mv = top[0];
#pragma unroll
        for (int q = 1; q < 8; ++q) { if (top[q] < mv) { mv = top[q]; ms = q; } }
#pragma unroll
        for (int q = 0; q < 8; ++q) top[q] = (q == ms) ? k : top[q];
        mv = top[0];
#pragma unroll
        for (int q = 1; q < 8; ++q) mv = (top[q] < mv) ? top[q] : mv;
        tmin = mv;
      }
    }
    unsigned* dst = part + ((size_t)(rbase + tid) * NS + split) * 8;
#pragma unroll
    for (int p = 0; p < 8; ++p) dst[p] = top[p];
  }
}

// ---------------- Kernel 3: merge splits, softmax, gather E, gate ----------------
// logits computed on x16-scaled operands -> raw dot = 256x; softmax input is
// TAU * dot / 256.
template<int NSP>
__global__ __launch_bounds__(256)
void k_gate(const unsigned* __restrict__ part, const float* __restrict__ target,
            const float* __restrict__ E, float* __restrict__ out) {
  constexpr int NK = NSP * 8;
  const int row = blockIdx.x;
  const int t = threadIdx.x;
  __shared__ float s_alpha[8];
  __shared__ int s_idx[8];
  __shared__ unsigned s_key[8];

  if (t < NK) {
    unsigned k = part[(size_t)row * NK + t];
#pragma unroll
    for (int p = 0; p < 8; ++p) {
      unsigned m = k;
#pragma unroll
      for (int off = NK / 2; off > 0; off >>= 1) {
        const unsigned o = __shfl_xor(m, off, NK);
        m = (m > o) ? m : o;
      }
      if (k == m) { s_key[p] = k; k = 0u; }  // keys distinct (idx in low bits)
    }
  }
  __syncthreads();
  if (t < 8) {
    const float SCALE = 10.0f / 256.0f;
    const unsigned key = s_key[t];
    const float val  = SCALE * sortable2f(key & ~0xFFFu);
    const float vmax = SCALE * sortable2f(s_key[0] & ~0xFFFu);
    const float e = expf(val - vmax);
    float s = e;
#pragma unroll
    for (int off = 4; off > 0; off >>= 1) s += __shfl_xor(s, off, 8);
    s_alpha[t] = e / s;
    s_idx[t] = (int)(key & 0xFFFu);
  }
  __syncthreads();

  float4 g = {0.f, 0.f, 0.f, 0.f};
#pragma unroll
  for (int p = 0; p < 8; ++p) {
    const float a = s_alpha[p];
    const float4 e4 = ((const float4*)E)[(size_t)s_idx[p] * 256 + t];
    g.x += a * e4.x;
    g.y += a * e4.y;
    g.z += a * e4.z;
    g.w += a * e4.w;
  }
  const float4 tg = ((const float4*)target)[(size_t)row * 256 + t];
  float4 o;
  o.x = tg.x * (1.f + g.x);
  o.y = tg.y * (1.f + g.y);
  o.z = tg.z * (1.f + g.z);
  o.w = tg.w * (1.f + g.w);
  ((float4*)out)[(size_t)row * 256 + t] = o;
}

extern "C" void kernel_launch(void* const* d_in, const int* in_sizes, int n_in,
                              void* d_out, int out_size, void* d_ws, size_t ws_size,
                              hipStream_t stream) {
  const float* z      = (const float*)d_in[0];
  const float* target = (const float*)d_in[1];
  const float* cb     = (const float*)d_in[2];
  const float* E      = (const float*)d_in[3];
  float* out = (float*)d_out;

  // d_out doubles as scratch for the fp8 normalized matrices (dead before k_gate writes)
  unsigned char* zf8  = (unsigned char*)d_out;                        // 16 MB
  unsigned char* cbf8 = (unsigned char*)d_out + 16777216;             // 4 MB @ +16MB
  unsigned* part = (unsigned*)d_ws;                                   // 4 MB

  k_normalize<<<dim3(M_ROWS + K_CB), dim3(256), 0, stream>>>(z, cb, zf8, cbf8);
  k_gemm_topk<<<dim3(MBLOCKS * NS), dim3(256), 0, stream>>>(zf8, cbf8, part);
  k_gate<NS><<<dim3(M_ROWS), dim3(256), 0, stream>>>(part, target, E, out);
}

// Round 19
// 211.554 us; speedup vs baseline: 4.8250x; 1.4340x over previous
//
#include <hip/hip_runtime.h>
#include <hip/hip_bf16.h>

#define M_ROWS 16384
#define D_DIM  1024
#define K_CB   4096

#define ZTILE  128               // z rows per block
#define CTILE  256               // cb entries per chunk
#define NS     8
#define COLS_PER_SPLIT (K_CB / NS)   // 512
#define BODIES 32                    // 2 chunks x 16 (K=1024 / 64 per body)
#define MBLOCKS (M_ROWS / ZTILE)     // 128

typedef __attribute__((ext_vector_type(4))) int  int4v;
typedef __attribute__((ext_vector_type(8))) int  int8v;
typedef __attribute__((ext_vector_type(16))) float f32x16;

static __device__ __forceinline__ unsigned f2sortable(float f) {
  unsigned u = __float_as_uint(f);
  return (u & 0x80000000u) ? ~u : (u | 0x80000000u);
}

static __device__ __forceinline__ float sortable2f(unsigned s) {
  unsigned u = (s & 0x80000000u) ? (s ^ 0x80000000u) : ~s;
  return __uint_as_float(u);
}

// OCP e4m3fn encode, RNE, satfinite.
static __device__ __forceinline__ unsigned char f2e4m3(float f) {
  float a = fabsf(f);
  const unsigned s = (__float_as_uint(f) >> 24) & 0x80u;
  if (a < 0.015625f) {                       // subnormal range (< 2^-6)
    int m = (int)(a * 512.0f + 0.5f);        // round(a / 2^-9)
    if (m >= 8) return (unsigned char)(s | 0x08u);   // -> 2^-6 normal
    return (unsigned char)(s | (unsigned)m);
  }
  if (a > 448.0f) a = 448.0f;
  unsigned t = __float_as_uint(a);
  t += 0x7FFFFu + ((t >> 20) & 1u);          // RNE to 3 mantissa bits
  int e = (int)(t >> 23) - 127;
  unsigned m = (t >> 20) & 7u;
  if (e > 8 || (e == 8 && m == 7u)) { e = 8; m = 6u; }   // clamp to 448
  return (unsigned char)(s | ((unsigned)(e + 7) << 3) | m);
}

static __device__ __forceinline__ void gload_lds16(const unsigned char* g, unsigned char* l) {
  __builtin_amdgcn_global_load_lds(
      (const __attribute__((address_space(1))) void*)g,
      (__attribute__((address_space(3))) void*)l, 16, 0, 0);
}

// ---------------- Kernel 1: l2-normalize rows -> fp8 e4m3 (x16, row-major) ----------------
// Output scaled by 16 (e4m3 sweet range); both operands scaled the same way
// -> dot x256, top-k order preserved; k3 rescales (SCALE = 10/256).
__global__ __launch_bounds__(256)
void k_normalize(const float* __restrict__ z, const float* __restrict__ cb,
                 unsigned char* __restrict__ zf8, unsigned char* __restrict__ cbf8) {
  const int bid = blockIdx.x;
  const float* src;
  unsigned char* dst;
  if (bid < M_ROWS) {
    src = z + (size_t)bid * D_DIM;
    dst = zf8 + (size_t)bid * D_DIM;
  } else {
    const int r = bid - M_ROWS;
    src = cb + (size_t)r * D_DIM;
    dst = cbf8 + (size_t)r * D_DIM;
  }
  const int t = threadIdx.x;
  const float4 v = ((const float4*)src)[t];
  float ss = v.x * v.x + v.y * v.y + v.z * v.z + v.w * v.w;
#pragma unroll
  for (int off = 32; off > 0; off >>= 1) ss += __shfl_down(ss, off, 64);
  __shared__ float sp[4];
  if ((t & 63) == 0) sp[t >> 6] = ss;
  __syncthreads();
  const float tot = sp[0] + sp[1] + sp[2] + sp[3];
  const float sc = 16.0f / sqrtf(tot + 1e-12f);     // l2norm * 16
  uchar4 o;
  o.x = f2e4m3(v.x * sc);
  o.y = f2e4m3(v.y * sc);
  o.z = f2e4m3(v.z * sc);
  o.w = f2e4m3(v.w * sc);
  *(uchar4*)(dst + 4 * t) = o;
}

// ---------------- Kernel 2: z128 x cb256 tile, MX-scaled fp8 32x32x64, BK=64 ----------------
// R16 base (139 us, passing) with ONE change: fragment loads go DIRECTLY into
// the halves of a named int8v (((int4v*)&cf)[0/1] = ds_read_b128) instead of
// shufflevector concat -- kills ~100 v_mov/body/wave (R16's VALUBusy 36% was
// the largest pipe; the movs were most of it). Addressing identical to R16:
// first half at cA (global slot 2*l5 = k [32*l5,32*l5+16)), second at cA^16.
// (R18 aside: direct global fragment loads are uncoalesced by layout --
// lane=row stride 1024B -- LDS staging is the layout transform; keep it.)
__global__ __launch_bounds__(256, 2)
void k_gemm_topk(const unsigned char* __restrict__ zf8,
                 const unsigned char* __restrict__ cbf8,
                 unsigned* __restrict__ part) {
  __shared__ __align__(16) unsigned char smem[49152];  // Z0|Z1 8KB each, C0|C1 16KB each

  const int tid  = threadIdx.x;
  const int lane = tid & 63;
  const int wid  = tid >> 6;
  const int wc   = wid & 1;    // cb 128-block
  const int wz   = wid >> 1;   // z 64-block
  const int l31  = lane & 31;
  const int l5   = lane >> 5;

  const int wgid  = (int)blockIdx.x;
  const int split = wgid & 7;          // xcd-resident codebook slab
  const int mtile = wgid >> 3;
  const int rbase = mtile * ZTILE;
  const int cbase = split * COLS_PER_SPLIT;

  // fragment byte bases: sigma0 = (2*l5) ^ rho(r); second b128 at base ^ 16
  int cA[4], zA[2];
#pragma unroll
  for (int mi = 0; mi < 4; ++mi) {
    const int r = wc * 128 + mi * 32 + l31;
    cA[mi] = r * 64 + (((2 * l5) ^ ((r >> 1) & 3)) << 4);
  }
#pragma unroll
  for (int nj = 0; nj < 2; ++nj) {
    const int r = wz * 64 + nj * 32 + l31;
    zA[nj] = r * 64 + (((2 * l5) ^ ((r >> 1) & 3)) << 4);
  }

  // staging: thread -> row t>>2, 16B slot t&3; source pre-swizzled (slot ^ rho(row)).
  const long stoff = (long)(tid >> 2) * D_DIM + (((tid & 3) ^ ((tid >> 3) & 3)) << 4);
  const unsigned char* zsp = zf8 + (size_t)rbase * D_DIM + stoff;
  const unsigned char* csp = cbf8 + (size_t)cbase * D_DIM + stoff;

  f32x16 acc[4][2];
#pragma unroll
  for (int mi = 0; mi < 4; ++mi)
#pragma unroll
    for (int nj = 0; nj < 2; ++nj)
#pragma unroll
      for (int r = 0; r < 16; ++r) acc[mi][nj][r] = 0.f;

  unsigned tk[2][8];                 // sorted ascending; tk[0] = min; pure u32
#pragma unroll
  for (int l = 0; l < 2; ++l)
#pragma unroll
    for (int q = 0; q < 8; ++q) tk[l][q] = 0u;

  auto STAGE = [&](int par) {
    unsigned char* zd = smem + par * 8192 + tid * 16;
    unsigned char* cd = smem + 16384 + par * 16384 + tid * 16;
    gload_lds16(zsp,                zd);
    gload_lds16(zsp +  64 * D_DIM,  zd + 4096);
    gload_lds16(csp,                cd);
    gload_lds16(csp +  64 * D_DIM,  cd + 4096);
    gload_lds16(csp + 128 * D_DIM,  cd + 8192);
    gload_lds16(csp + 192 * D_DIM,  cd + 12288);
  };
  auto ADV = [&](int stagedBody) {
    if (((stagedBody + 1) & 15) == 0) {
      zsp += 64 - D_DIM;                       // Z k-tiles repeat each chunk
      csp += 64 + (CTILE * D_DIM - D_DIM);     // C -> next 256-entry slab
    } else {
      zsp += 64; csp += 64;
    }
  };
  auto COMPUTE = [&](int par) {
    const unsigned char* Z = smem + par * 8192;
    const unsigned char* C = smem + 16384 + par * 16384;
    int8v cf[4], zr[2];
#pragma unroll
    for (int mi = 0; mi < 4; ++mi) {
      ((int4v*)&cf[mi])[0] = *(const int4v*)(C + cA[mi]);
      ((int4v*)&cf[mi])[1] = *(const int4v*)(C + (cA[mi] ^ 16));
    }
#pragma unroll
    for (int nj = 0; nj < 2; ++nj) {
      ((int4v*)&zr[nj])[0] = *(const int4v*)(Z + zA[nj]);
      ((int4v*)&zr[nj])[1] = *(const int4v*)(Z + (zA[nj] ^ 16));
    }
    __builtin_amdgcn_s_setprio(1);
#pragma unroll
    for (int mi = 0; mi < 4; ++mi)
#pragma unroll
      for (int nj = 0; nj < 2; ++nj)
        acc[mi][nj] = __builtin_amdgcn_mfma_scale_f32_32x32x64_f8f6f4(
            cf[mi], zr[nj], acc[mi][nj],
            0 /*A=fp8 e4m3*/, 0 /*B=fp8 e4m3*/, 0, 0x7F, 0, 0x7F);
    __builtin_amdgcn_s_setprio(0);
  };
  auto EPILOGUE = [&](int chunk) {
    const int cfb0 = cbase + chunk * CTILE + wc * 128 + l5 * 4;
#pragma unroll
    for (int nj = 0; nj < 2; ++nj) {
#pragma unroll
      for (int mi = 0; mi < 4; ++mi) {
#pragma unroll
        for (int r = 0; r < 16; ++r) {
          const float v = acc[mi][nj][r];
          const unsigned idx = (unsigned)(cfb0 + mi * 32 + (r & 3) + ((r >> 2) << 3));
          const unsigned key = (f2sortable(v) & ~0xFFFu) | idx;
          if (key > tk[nj][0]) {               // pure u32 gate; sorted insert
            unsigned cur = key;
#pragma unroll
            for (int q = 0; q < 7; ++q) {
              const unsigned a = tk[nj][q + 1];
              tk[nj][q] = (a < cur) ? a : cur;
              cur       = (a < cur) ? cur : a;
            }
            tk[nj][7] = cur;
          }
          acc[mi][nj][r] = 0.f;
        }
      }
    }
  };

  // prologue: stage body 0 -> buf0
  STAGE(0);
  ADV(0);
  __syncthreads();

  for (int b = 0; b < BODIES; b += 2) {
    STAGE(1);              // body b+1 -> buf1
    ADV(b + 1);
    COMPUTE(0);
    __syncthreads();

    if (b + 2 < BODIES) {
      STAGE(0);            // body b+2 -> buf0
      ADV(b + 2);
    }
    COMPUTE(1);
    if ((b & 15) == 14) EPILOGUE((b + 1) >> 4);   // chunks end at bodies 15/31
    __syncthreads();
  }

  // merge: per z row 4 contributors (wc x l5) x 8 keys -> LDS, then top-8 scan
  unsigned* mrg = (unsigned*)smem;     // [128][33] u32 = 16.9 KB
  {
    const int slotw = (wc * 2 + l5) * 8;
#pragma unroll
    for (int nj = 0; nj < 2; ++nj) {
      const int zrow = wz * 64 + nj * 32 + l31;
#pragma unroll
      for (int q = 0; q < 8; ++q) mrg[zrow * 33 + slotw + q] = tk[nj][q];
    }
  }
  __syncthreads();
  if (tid < ZTILE) {
    const unsigned* c = mrg + tid * 33;
    unsigned top[8];
#pragma unroll
    for (int p = 0; p < 8; ++p) top[p] = 0u;
    unsigned tmin = 0u;
    for (int q0 = 0; q0 < 32; ++q0) {
      const unsigned k = c[(q0 + tid) & 31];   // rotate to spread banks
      if (k > tmin) {
        int ms = 0;
        unsigned mv = top[0];
#pragma unroll
        for (int q = 1; q < 8; ++q) { if (top[q] < mv) { mv = top[q]; ms = q; } }
#pragma unroll
        for (int q = 0; q < 8; ++q) top[q] = (q == ms) ? k : top[q];
        mv = top[0];
#pragma unroll
        for (int q = 1; q < 8; ++q) mv = (top[q] < mv) ? top[q] : mv;
        tmin = mv;
      }
    }
    unsigned* dst = part + ((size_t)(rbase + tid) * NS + split) * 8;
#pragma unroll
    for (int p = 0; p < 8; ++p) dst[p] = top[p];
  }
}

// ---------------- Kernel 3: merge splits, softmax, gather E, gate ----------------
// logits computed on x16-scaled operands -> raw dot = 256x; softmax input is
// TAU * dot / 256.
template<int NSP>
__global__ __launch_bounds__(256)
void k_gate(const unsigned* __restrict__ part, const float* __restrict__ target,
            const float* __restrict__ E, float* __restrict__ out) {
  constexpr int NK = NSP * 8;
  const int row = blockIdx.x;
  const int t = threadIdx.x;
  __shared__ float s_alpha[8];
  __shared__ int s_idx[8];
  __shared__ unsigned s_key[8];

  if (t < NK) {
    unsigned k = part[(size_t)row * NK + t];
#pragma unroll
    for (int p = 0; p < 8; ++p) {
      unsigned m = k;
#pragma unroll
      for (int off = NK / 2; off > 0; off >>= 1) {
        const unsigned o = __shfl_xor(m, off, NK);
        m = (m > o) ? m : o;
      }
      if (k == m) { s_key[p] = k; k = 0u; }  // keys distinct (idx in low bits)
    }
  }
  __syncthreads();
  if (t < 8) {
    const float SCALE = 10.0f / 256.0f;
    const unsigned key = s_key[t];
    const float val  = SCALE * sortable2f(key & ~0xFFFu);
    const float vmax = SCALE * sortable2f(s_key[0] & ~0xFFFu);
    const float e = expf(val - vmax);
    float s = e;
#pragma unroll
    for (int off = 4; off > 0; off >>= 1) s += __shfl_xor(s, off, 8);
    s_alpha[t] = e / s;
    s_idx[t] = (int)(key & 0xFFFu);
  }
  __syncthreads();

  float4 g = {0.f, 0.f, 0.f, 0.f};
#pragma unroll
  for (int p = 0; p < 8; ++p) {
    const float a = s_alpha[p];
    const float4 e4 = ((const float4*)E)[(size_t)s_idx[p] * 256 + t];
    g.x += a * e4.x;
    g.y += a * e4.y;
    g.z += a * e4.z;
    g.w += a * e4.w;
  }
  const float4 tg = ((const float4*)target)[(size_t)row * 256 + t];
  float4 o;
  o.x = tg.x * (1.f + g.x);
  o.y = tg.y * (1.f + g.y);
  o.z = tg.z * (1.f + g.z);
  o.w = tg.w * (1.f + g.w);
  ((float4*)out)[(size_t)row * 256 + t] = o;
}

extern "C" void kernel_launch(void* const* d_in, const int* in_sizes, int n_in,
                              void* d_out, int out_size, void* d_ws, size_t ws_size,
                              hipStream_t stream) {
  const float* z      = (const float*)d_in[0];
  const float* target = (const float*)d_in[1];
  const float* cb     = (const float*)d_in[2];
  const float* E      = (const float*)d_in[3];
  float* out = (float*)d_out;

  // d_out doubles as scratch for the fp8 normalized matrices (dead before k_gate writes)
  unsigned char* zf8  = (unsigned char*)d_out;                        // 16 MB
  unsigned char* cbf8 = (unsigned char*)d_out + 16777216;             // 4 MB @ +16MB
  unsigned* part = (unsigned*)d_ws;                                   // 4 MB

  k_normalize<<<dim3(M_ROWS + K_CB), dim3(256), 0, stream>>>(z, cb, zf8, cbf8);
  k_gemm_topk<<<dim3(MBLOCKS * NS), dim3(256), 0, stream>>>(zf8, cbf8, part);
  k_gate<NS><<<dim3(M_ROWS), dim3(256), 0, stream>>>(part, target, E, out);
}